// Round 1
// baseline (461.987 us; speedup 1.0000x reference)
//
#include <hip/hip_runtime.h>
#include <stdint.h>

#define B_ 4
#define S_ 2048
#define D_ 1024
#define H_ 16

typedef __attribute__((ext_vector_type(4))) float f32x4;
typedef __attribute__((ext_vector_type(8))) short short8;
typedef __attribute__((ext_vector_type(8))) unsigned short ushort8;
typedef unsigned short u16;

__device__ __forceinline__ u16 f2bf(float f){
  unsigned u = __builtin_bit_cast(unsigned, f);
  return (u16)((u + 0x7FFFu + ((u >> 16) & 1u)) >> 16);
}
__device__ __forceinline__ float bf2f(u16 h){
  return __builtin_bit_cast(float, ((unsigned)h) << 16);
}
__device__ __forceinline__ f32x4 mfma16(short8 a, short8 b, f32x4 c){
  return __builtin_amdgcn_mfma_f32_16x16x32_bf16(a, b, c, 0, 0, 0);
}

// ---------------- fp32 -> bf16 convert (4 elem / thread) ----------------
__global__ __launch_bounds__(256) void cvt_kernel(const float* __restrict__ in,
                                                  u16* __restrict__ out, int n4){
  int i = blockIdx.x * 256 + threadIdx.x;
  if (i >= n4) return;
  float4 v = reinterpret_cast<const float4*>(in)[i];
  uint2 o;
  o.x = (unsigned)f2bf(v.x) | ((unsigned)f2bf(v.y) << 16);
  o.y = (unsigned)f2bf(v.z) | ((unsigned)f2bf(v.w) << 16);
  reinterpret_cast<uint2*>(out)[i] = o;
}

// ---------------- GEMM: C[M,N] = A[M,K] * B[N,K]^T (bf16 in, MODE out) ----
// MODE 0: bf16 row-major [M][N]; MODE 1: bf16 [B,H,S,HD]; MODE 2: f32 [M][N]
template<int MODE>
__global__ __launch_bounds__(256) void gemm_bt(const u16* __restrict__ A,
                                               const u16* __restrict__ Bw,
                                               void* __restrict__ C,
                                               int M, int N, int K){
  __shared__ __align__(16) u16 As[128*32];
  __shared__ __align__(16) u16 Bs[128*32];
  const int tid = threadIdx.x;
  const int lane = tid & 63, wid = tid >> 6;
  const int l16 = lane & 15, lq = lane >> 4;
  const int m0 = blockIdx.y * 128, n0 = blockIdx.x * 128;
  const int wr = (wid >> 1) * 64, wc = (wid & 1) * 64;
  const int sr = tid >> 2;            // staging row 0..63
  const int scc = (tid & 3) * 8;      // staging col (elems)
  f32x4 acc[4][4] = {};
  for (int k0 = 0; k0 < K; k0 += 32){
    __syncthreads();
    ushort8 a0 = *reinterpret_cast<const ushort8*>(A  + (size_t)(m0 + sr     ) * K + k0 + scc);
    ushort8 a1 = *reinterpret_cast<const ushort8*>(A  + (size_t)(m0 + sr + 64) * K + k0 + scc);
    ushort8 b0 = *reinterpret_cast<const ushort8*>(Bw + (size_t)(n0 + sr     ) * K + k0 + scc);
    ushort8 b1 = *reinterpret_cast<const ushort8*>(Bw + (size_t)(n0 + sr + 64) * K + k0 + scc);
    *reinterpret_cast<ushort8*>(As + sr*32 + scc)      = a0;
    *reinterpret_cast<ushort8*>(As + (sr+64)*32 + scc) = a1;
    *reinterpret_cast<ushort8*>(Bs + sr*32 + scc)      = b0;
    *reinterpret_cast<ushort8*>(Bs + (sr+64)*32 + scc) = b1;
    __syncthreads();
    short8 af[4], bfr[4];
#pragma unroll
    for (int i=0;i<4;i++) af[i]  = *reinterpret_cast<const short8*>(As + (wr + i*16 + l16)*32 + lq*8);
#pragma unroll
    for (int i=0;i<4;i++) bfr[i] = *reinterpret_cast<const short8*>(Bs + (wc + i*16 + l16)*32 + lq*8);
#pragma unroll
    for (int i=0;i<4;i++)
#pragma unroll
      for (int j=0;j<4;j++) acc[i][j] = mfma16(af[i], bfr[j], acc[i][j]);
  }
#pragma unroll
  for (int i=0;i<4;i++){
#pragma unroll
    for (int j=0;j<4;j++){
#pragma unroll
      for (int r=0;r<4;r++){
        const int m = m0 + wr + i*16 + lq*4 + r;
        const int n = n0 + wc + j*16 + l16;
        const float v = acc[i][j][r];
        if (MODE == 2){
          reinterpret_cast<float*>(C)[(size_t)m * N + n] = v;
        } else if (MODE == 0){
          reinterpret_cast<u16*>(C)[(size_t)m * N + n] = f2bf(v);
        } else {
          const int b = m >> 11, s = m & 2047;    // S_=2048
          const int h = n >> 6,  hd = n & 63;     // HD=64
          reinterpret_cast<u16*>(C)[(((size_t)(b*H_ + h) * S_ + s) << 6) + hd] = f2bf(v);
        }
      }
    }
  }
}

// ---------------- RoPE in place on Q,K stored [B*H][S][64] ----------------
__global__ __launch_bounds__(256) void rope_kernel(u16* __restrict__ Q, u16* __restrict__ Kk){
  const int idx = blockIdx.x * 256 + threadIdx.x;   // (bh:6)(s:11)(i:5)
  const int i  = idx & 31;
  const int s  = (idx >> 5) & 2047;
  const int bh = idx >> 16;
  const float ang = (float)s * __expf((float)i * -0.2878231366242557f); // theta^(-i/32)
  float sn, cs;
  __sincosf(ang, &sn, &cs);
  const size_t base = ((size_t)bh * S_ + s) * 64 + 2*i;
  {
    unsigned q = *reinterpret_cast<unsigned*>(Q + base);
    float x1 = bf2f((u16)q), x2 = bf2f((u16)(q >> 16));
    *reinterpret_cast<unsigned*>(Q + base) =
      (unsigned)f2bf(x1*cs - x2*sn) | ((unsigned)f2bf(x1*sn + x2*cs) << 16);
  }
  {
    unsigned k = *reinterpret_cast<unsigned*>(Kk + base);
    float x1 = bf2f((u16)k), x2 = bf2f((u16)(k >> 16));
    *reinterpret_cast<unsigned*>(Kk + base) =
      (unsigned)f2bf(x1*cs - x2*sn) | ((unsigned)f2bf(x1*sn + x2*cs) << 16);
  }
}

// ---------------- V [B,S,D] -> V^T [B*H][HD=64][S] ----------------
__global__ __launch_bounds__(256) void vt_kernel(const u16* __restrict__ V, u16* __restrict__ Vt){
  __shared__ __align__(16) u16 t[64*80];
  const int bh = blockIdx.y, b = bh >> 4, h = bh & 15;
  const int s0 = blockIdx.x * 64;
  const int tid = threadIdx.x;
  const int r = tid >> 3, seg = tid & 7;
#pragma unroll
  for (int p=0;p<2;p++){
    const int row = r + p*32;   // s offset
    ushort8 v = *reinterpret_cast<const ushort8*>(V + (size_t)(b*S_ + s0 + row)*D_ + h*64 + seg*8);
    *reinterpret_cast<ushort8*>(t + row*80 + seg*8) = v;
  }
  __syncthreads();
#pragma unroll
  for (int p=0;p<2;p++){
    const int hd = r + p*32;
    ushort8 o;
#pragma unroll
    for (int j=0;j<8;j++) o[j] = t[(seg*8+j)*80 + hd];
    *reinterpret_cast<ushort8*>(Vt + ((size_t)bh*64 + hd)*S_ + s0 + seg*8) = o;
  }
}

// ---------------- causal flash attention ----------------
// Q,K: [BH][S][64] (roped), Vt: [BH][64][S], O: [B,S,D] bf16
__global__ __launch_bounds__(256) void attn_kernel(const u16* __restrict__ Q,
                                                   const u16* __restrict__ Kg,
                                                   const u16* __restrict__ Vt,
                                                   u16* __restrict__ O){
  __shared__ __align__(16) u16 Ks[64*64];
  __shared__ __align__(16) u16 Vs[64*64];
  __shared__ __align__(16) u16 Ps[4][16*64];
  const int qt = blockIdx.x, bh = blockIdx.y;
  const int tid = threadIdx.x, wid = tid >> 6, lane = tid & 63;
  const int l16 = lane & 15, lq = lane >> 4;
  const int q0 = qt * 64;
  const u16* Qb = Q  + (size_t)bh * S_ * 64;
  const u16* Kb = Kg + (size_t)bh * S_ * 64;
  const u16* Vb = Vt + (size_t)bh * 64 * S_;
  short8 qf[2];
#pragma unroll
  for (int ks=0;ks<2;ks++)
    qf[ks] = *reinterpret_cast<const short8*>(Qb + (size_t)(q0 + wid*16 + l16)*64 + ks*32 + lq*8);
  float m_run[4], l_run[4];
  f32x4 oacc[4];
#pragma unroll
  for (int j=0;j<4;j++){ m_run[j] = -1e30f; l_run[j] = 0.f; oacc[j] = (f32x4){0.f,0.f,0.f,0.f}; }
  const int sr2 = tid >> 3, sc2 = (tid & 7) * 8;
  for (int kt = 0; kt <= qt; ++kt){
    const int k0 = kt * 64;
    __syncthreads();
#pragma unroll
    for (int p=0;p<2;p++){
      const int row = sr2 + p*32;
      *reinterpret_cast<ushort8*>(Ks + row*64 + sc2) =
        *reinterpret_cast<const ushort8*>(Kb + (size_t)(k0 + row)*64 + sc2);
      *reinterpret_cast<ushort8*>(Vs + row*64 + sc2) =
        *reinterpret_cast<const ushort8*>(Vb + (size_t)row*S_ + k0 + sc2);
    }
    __syncthreads();
    f32x4 sc[4];
#pragma unroll
    for (int ct=0;ct<4;ct++){
      f32x4 a = (f32x4){0.f,0.f,0.f,0.f};
#pragma unroll
      for (int ks=0;ks<2;ks++){
        short8 kf = *reinterpret_cast<const short8*>(Ks + (ct*16 + l16)*64 + ks*32 + lq*8);
        a = mfma16(qf[ks], kf, a);
      }
      sc[ct] = a;
    }
#pragma unroll
    for (int ct=0;ct<4;ct++){
      const int kg = k0 + ct*16 + l16;
#pragma unroll
      for (int r=0;r<4;r++){
        const int qg = q0 + wid*16 + lq*4 + r;
        sc[ct][r] = (kg <= qg) ? sc[ct][r]*0.125f : -1e30f;
      }
    }
#pragma unroll
    for (int r=0;r<4;r++){
      float mx = fmaxf(fmaxf(sc[0][r], sc[1][r]), fmaxf(sc[2][r], sc[3][r]));
#pragma unroll
      for (int msk=1; msk<16; msk<<=1) mx = fmaxf(mx, __shfl_xor(mx, msk, 64));
      const float mn = fmaxf(m_run[r], mx);
      const float alpha = __expf(m_run[r] - mn);
      m_run[r] = mn;
      float sum = 0.f;
#pragma unroll
      for (int ct=0;ct<4;ct++){
        const float p = __expf(sc[ct][r] - mn);
        sc[ct][r] = p;
        sum += p;
      }
#pragma unroll
      for (int msk=1; msk<16; msk<<=1) sum += __shfl_xor(sum, msk, 64);
      l_run[r] = l_run[r]*alpha + sum;
#pragma unroll
      for (int dt=0;dt<4;dt++) oacc[dt][r] *= alpha;
    }
    u16* Pw = &Ps[wid][0];
#pragma unroll
    for (int ct=0;ct<4;ct++)
#pragma unroll
      for (int r=0;r<4;r++)
        Pw[(lq*4 + r)*64 + ct*16 + l16] = f2bf(sc[ct][r]);
    asm volatile("s_waitcnt lgkmcnt(0)" ::: "memory");
#pragma unroll
    for (int ks=0;ks<2;ks++){
      short8 pf = *reinterpret_cast<const short8*>(Pw + l16*64 + ks*32 + lq*8);
#pragma unroll
      for (int dt=0;dt<4;dt++){
        short8 vf = *reinterpret_cast<const short8*>(Vs + (dt*16 + l16)*64 + ks*32 + lq*8);
        oacc[dt] = mfma16(pf, vf, oacc[dt]);
      }
    }
  }
  const int b = bh >> 4, h = bh & 15;
#pragma unroll
  for (int dt=0;dt<4;dt++)
#pragma unroll
    for (int r=0;r<4;r++){
      const int qg = q0 + wid*16 + lq*4 + r;
      O[(size_t)(b*S_ + qg)*D_ + h*64 + dt*16 + l16] = f2bf(oacc[dt][r] / l_run[r]);
    }
}

extern "C" void kernel_launch(void* const* d_in, const int* in_sizes, int n_in,
                              void* d_out, int out_size, void* d_ws, size_t ws_size,
                              hipStream_t stream){
  const float* x  = (const float*)d_in[0];
  const float* Wq = (const float*)d_in[1];
  const float* Wk = (const float*)d_in[2];
  const float* Wv = (const float*)d_in[3];
  const float* Wo = (const float*)d_in[4];
  char* ws = (char*)d_ws;
  // workspace layout (bytes); total 88 MiB
  u16* xb  = (u16*)(ws);                               // 16 MiB  x bf16
  u16* Wqb = (u16*)(ws + (16u<<20));                   // 2 MiB
  u16* Wkb = (u16*)(ws + (16u<<20) + (2u<<20));
  u16* Wvb = (u16*)(ws + (16u<<20) + (4u<<20));
  u16* Wob = (u16*)(ws + (16u<<20) + (6u<<20));
  u16* Qh  = (u16*)(ws + (24u<<20));                   // 16 MiB [BH][S][64]
  u16* Kh  = (u16*)(ws + (40u<<20));                   // 16 MiB
  u16* Vb  = (u16*)(ws + (56u<<20));                   // 16 MiB [B,S,D]
  u16* Vt  = (u16*)(ws + (72u<<20));                   // 16 MiB [BH][64][S]
  u16* Ob  = Vb;                                       // alias: V dead after vt_kernel

  cvt_kernel<<<8192, 256, 0, stream>>>(x,  xb,  2097152);
  cvt_kernel<<<1024, 256, 0, stream>>>(Wq, Wqb, 262144);
  cvt_kernel<<<1024, 256, 0, stream>>>(Wk, Wkb, 262144);
  cvt_kernel<<<1024, 256, 0, stream>>>(Wv, Wvb, 262144);
  cvt_kernel<<<1024, 256, 0, stream>>>(Wo, Wob, 262144);

  dim3 gg(8, 64);
  gemm_bt<1><<<gg, 256, 0, stream>>>(xb, Wqb, Qh, 8192, 1024, 1024);
  gemm_bt<1><<<gg, 256, 0, stream>>>(xb, Wkb, Kh, 8192, 1024, 1024);
  gemm_bt<0><<<gg, 256, 0, stream>>>(xb, Wvb, Vb, 8192, 1024, 1024);

  rope_kernel<<<16384, 256, 0, stream>>>(Qh, Kh);
  vt_kernel<<<dim3(32,64), 256, 0, stream>>>(Vb, Vt);
  attn_kernel<<<dim3(32,64), 256, 0, stream>>>(Qh, Kh, Vt, Ob);

  gemm_bt<2><<<gg, 256, 0, stream>>>(Ob, Wob, d_out, 8192, 1024, 1024);
}

// Round 2
// 295.666 us; speedup vs baseline: 1.5625x; 1.5625x over previous
//
#include <hip/hip_runtime.h>
#include <stdint.h>

#define B_ 4
#define S_ 2048
#define D_ 1024
#define H_ 16

typedef __attribute__((ext_vector_type(4))) float f32x4;
typedef __attribute__((ext_vector_type(8))) short short8;
typedef __attribute__((ext_vector_type(8))) unsigned short ushort8;
typedef unsigned short u16;

__device__ __forceinline__ u16 f2bf(float f){
  unsigned u = __builtin_bit_cast(unsigned, f);
  return (u16)((u + 0x7FFFu + ((u >> 16) & 1u)) >> 16);
}
__device__ __forceinline__ float bf2f(u16 h){
  return __builtin_bit_cast(float, ((unsigned)h) << 16);
}
__device__ __forceinline__ f32x4 mfma16(short8 a, short8 b, f32x4 c){
  return __builtin_amdgcn_mfma_f32_16x16x32_bf16(a, b, c, 0, 0, 0);
}

// ---------------- fp32 -> bf16 convert (4 elem / thread) ----------------
__global__ __launch_bounds__(256) void cvt_kernel(const float* __restrict__ in,
                                                  u16* __restrict__ out, int n4){
  int i = blockIdx.x * 256 + threadIdx.x;
  if (i >= n4) return;
  float4 v = reinterpret_cast<const float4*>(in)[i];
  uint2 o;
  o.x = (unsigned)f2bf(v.x) | ((unsigned)f2bf(v.y) << 16);
  o.y = (unsigned)f2bf(v.z) | ((unsigned)f2bf(v.w) << 16);
  reinterpret_cast<uint2*>(out)[i] = o;
}

// ---------------- GEMM: C[M,N] = A[M,K] * B[N,K]^T (bf16 in, MODE out) ----
// MODE 0: bf16 row-major [M][N]; MODE 1: bf16 [B,H,S,HD]; MODE 2: f32 [M][N]
// LDS rows padded 32->40 u16 (80B): bank stride 20 == +4 mod 32 -> 2-way max.
#define GPAD 40
template<int MODE>
__global__ __launch_bounds__(256) void gemm_bt(const u16* __restrict__ A,
                                               const u16* __restrict__ Bw,
                                               void* __restrict__ C,
                                               int M, int N, int K){
  __shared__ __align__(16) u16 As[128*GPAD];
  __shared__ __align__(16) u16 Bs[128*GPAD];
  const int tid = threadIdx.x;
  const int lane = tid & 63, wid = tid >> 6;
  const int l16 = lane & 15, lq = lane >> 4;
  const int m0 = blockIdx.y * 128, n0 = blockIdx.x * 128;
  const int wr = (wid >> 1) * 64, wc = (wid & 1) * 64;
  const int sr = tid >> 2;            // staging row 0..63
  const int scc = (tid & 3) * 8;      // staging col (elems)
  f32x4 acc[4][4] = {};
  for (int k0 = 0; k0 < K; k0 += 32){
    __syncthreads();
    ushort8 a0 = *reinterpret_cast<const ushort8*>(A  + (size_t)(m0 + sr     ) * K + k0 + scc);
    ushort8 a1 = *reinterpret_cast<const ushort8*>(A  + (size_t)(m0 + sr + 64) * K + k0 + scc);
    ushort8 b0 = *reinterpret_cast<const ushort8*>(Bw + (size_t)(n0 + sr     ) * K + k0 + scc);
    ushort8 b1 = *reinterpret_cast<const ushort8*>(Bw + (size_t)(n0 + sr + 64) * K + k0 + scc);
    *reinterpret_cast<ushort8*>(As + sr*GPAD + scc)      = a0;
    *reinterpret_cast<ushort8*>(As + (sr+64)*GPAD + scc) = a1;
    *reinterpret_cast<ushort8*>(Bs + sr*GPAD + scc)      = b0;
    *reinterpret_cast<ushort8*>(Bs + (sr+64)*GPAD + scc) = b1;
    __syncthreads();
    short8 af[4], bfr[4];
#pragma unroll
    for (int i=0;i<4;i++) af[i]  = *reinterpret_cast<const short8*>(As + (wr + i*16 + l16)*GPAD + lq*8);
#pragma unroll
    for (int i=0;i<4;i++) bfr[i] = *reinterpret_cast<const short8*>(Bs + (wc + i*16 + l16)*GPAD + lq*8);
#pragma unroll
    for (int i=0;i<4;i++)
#pragma unroll
      for (int j=0;j<4;j++) acc[i][j] = mfma16(af[i], bfr[j], acc[i][j]);
  }
#pragma unroll
  for (int i=0;i<4;i++){
#pragma unroll
    for (int j=0;j<4;j++){
#pragma unroll
      for (int r=0;r<4;r++){
        const int m = m0 + wr + i*16 + lq*4 + r;
        const int n = n0 + wc + j*16 + l16;
        const float v = acc[i][j][r];
        if (MODE == 2){
          reinterpret_cast<float*>(C)[(size_t)m * N + n] = v;
        } else if (MODE == 0){
          reinterpret_cast<u16*>(C)[(size_t)m * N + n] = f2bf(v);
        } else {
          const int b = m >> 11, s = m & 2047;    // S_=2048
          const int h = n >> 6,  hd = n & 63;     // HD=64
          reinterpret_cast<u16*>(C)[(((size_t)(b*H_ + h) * S_ + s) << 6) + hd] = f2bf(v);
        }
      }
    }
  }
}

// ---------------- RoPE in place on Q,K stored [B*H][S][64] ----------------
// Q additionally scaled by 1/sqrt(HD) = 0.125 (folded softmax scale).
__global__ __launch_bounds__(256) void rope_kernel(u16* __restrict__ Q, u16* __restrict__ Kk){
  const int idx = blockIdx.x * 256 + threadIdx.x;   // (bh:6)(s:11)(i:5)
  const int i  = idx & 31;
  const int s  = (idx >> 5) & 2047;
  const int bh = idx >> 16;
  const float ang = (float)s * __expf((float)i * -0.2878231366242557f); // theta^(-i/32)
  float sn, cs;
  __sincosf(ang, &sn, &cs);
  const size_t base = ((size_t)bh * S_ + s) * 64 + 2*i;
  {
    unsigned q = *reinterpret_cast<unsigned*>(Q + base);
    float x1 = bf2f((u16)q), x2 = bf2f((u16)(q >> 16));
    *reinterpret_cast<unsigned*>(Q + base) =
      (unsigned)f2bf((x1*cs - x2*sn)*0.125f) | ((unsigned)f2bf((x1*sn + x2*cs)*0.125f) << 16);
  }
  {
    unsigned k = *reinterpret_cast<unsigned*>(Kk + base);
    float x1 = bf2f((u16)k), x2 = bf2f((u16)(k >> 16));
    *reinterpret_cast<unsigned*>(Kk + base) =
      (unsigned)f2bf(x1*cs - x2*sn) | ((unsigned)f2bf(x1*sn + x2*cs) << 16);
  }
}

// ---------------- V [B,S,D] -> V^T [B*H][HD=64][S] ----------------
__global__ __launch_bounds__(256) void vt_kernel(const u16* __restrict__ V, u16* __restrict__ Vt){
  __shared__ __align__(16) u16 t[64*80];
  const int bh = blockIdx.y, b = bh >> 4, h = bh & 15;
  const int s0 = blockIdx.x * 64;
  const int tid = threadIdx.x;
  const int r = tid >> 3, seg = tid & 7;
#pragma unroll
  for (int p=0;p<2;p++){
    const int row = r + p*32;   // s offset
    ushort8 v = *reinterpret_cast<const ushort8*>(V + (size_t)(b*S_ + s0 + row)*D_ + h*64 + seg*8);
    *reinterpret_cast<ushort8*>(t + row*80 + seg*8) = v;
  }
  __syncthreads();
#pragma unroll
  for (int p=0;p<2;p++){
    const int hd = r + p*32;
    ushort8 o;
#pragma unroll
    for (int j=0;j<8;j++) o[j] = t[(seg*8+j)*80 + hd];
    *reinterpret_cast<ushort8*>(Vt + ((size_t)bh*64 + hd)*S_ + s0 + seg*8) = o;
  }
}

// ---------------- causal flash attention ----------------
// Q,K: [BH][S][64] (Q pre-scaled+roped), Vt: [BH][64][S], O: [B,S,D] bf16
// LDS rows padded 64->72 u16 (144B): bank stride 36 == +4 mod 32.
// Work balance: block (bx,bh) processes q-tiles {31-bx, bx}: 33 KV-tiles each.
#define APAD 72
__global__ __launch_bounds__(256) void attn_kernel(const u16* __restrict__ Q,
                                                   const u16* __restrict__ Kg,
                                                   const u16* __restrict__ Vt,
                                                   u16* __restrict__ O){
  __shared__ __align__(16) u16 Ks[64*APAD];
  __shared__ __align__(16) u16 Vs[64*APAD];
  __shared__ __align__(16) u16 Ps[4][16*APAD];
  const int bh = blockIdx.y;
  const int tid = threadIdx.x, wid = tid >> 6, lane = tid & 63;
  const int l16 = lane & 15, lq = lane >> 4;
  const u16* Qb = Q  + (size_t)bh * S_ * 64;
  const u16* Kb = Kg + (size_t)bh * S_ * 64;
  const u16* Vb = Vt + (size_t)bh * 64 * S_;
  const int b = bh >> 4, h = bh & 15;
  const int sr2 = tid >> 3, sc2 = (tid & 7) * 8;
  u16* Pw = &Ps[wid][0];

#pragma unroll 1
  for (int half = 0; half < 2; ++half){
    const int qt = half ? blockIdx.x : (31 - blockIdx.x);
    const int q0 = qt * 64;
    short8 qf[2];
#pragma unroll
    for (int ks=0;ks<2;ks++)
      qf[ks] = *reinterpret_cast<const short8*>(Qb + (size_t)(q0 + wid*16 + l16)*64 + ks*32 + lq*8);
    float m_run[4], l_run[4];
    f32x4 oacc[4];
#pragma unroll
    for (int j=0;j<4;j++){ m_run[j] = -1e30f; l_run[j] = 0.f; oacc[j] = (f32x4){0.f,0.f,0.f,0.f}; }

    for (int kt = 0; kt <= qt; ++kt){
      const int k0 = kt * 64;
      __syncthreads();
#pragma unroll
      for (int p=0;p<2;p++){
        const int row = sr2 + p*32;
        *reinterpret_cast<ushort8*>(Ks + row*APAD + sc2) =
          *reinterpret_cast<const ushort8*>(Kb + (size_t)(k0 + row)*64 + sc2);
        *reinterpret_cast<ushort8*>(Vs + row*APAD + sc2) =
          *reinterpret_cast<const ushort8*>(Vb + (size_t)row*S_ + k0 + sc2);
      }
      __syncthreads();
      f32x4 sc[4];
#pragma unroll
      for (int ct=0;ct<4;ct++){
        f32x4 a = (f32x4){0.f,0.f,0.f,0.f};
#pragma unroll
        for (int ks=0;ks<2;ks++){
          short8 kf = *reinterpret_cast<const short8*>(Ks + (ct*16 + l16)*APAD + ks*32 + lq*8);
          a = mfma16(qf[ks], kf, a);
        }
        sc[ct] = a;
      }
      if (kt == qt){   // mask only the diagonal tile
#pragma unroll
        for (int ct=0;ct<4;ct++){
          const int kg = ct*16 + l16;
#pragma unroll
          for (int r=0;r<4;r++){
            const int qg = wid*16 + lq*4 + r;
            if (kg > qg) sc[ct][r] = -1e30f;
          }
        }
      }
#pragma unroll
      for (int r=0;r<4;r++){
        float mx = fmaxf(fmaxf(sc[0][r], sc[1][r]), fmaxf(sc[2][r], sc[3][r]));
#pragma unroll
        for (int msk=1; msk<16; msk<<=1) mx = fmaxf(mx, __shfl_xor(mx, msk, 64));
        const float mn = fmaxf(m_run[r], mx);
        const float alpha = __expf(m_run[r] - mn);
        m_run[r] = mn;
        float sum = 0.f;
#pragma unroll
        for (int ct=0;ct<4;ct++){
          const float p = __expf(sc[ct][r] - mn);
          sc[ct][r] = p;
          sum += p;
        }
#pragma unroll
        for (int msk=1; msk<16; msk<<=1) sum += __shfl_xor(sum, msk, 64);
        l_run[r] = l_run[r]*alpha + sum;
#pragma unroll
        for (int dt=0;dt<4;dt++) oacc[dt][r] *= alpha;
      }
#pragma unroll
      for (int ct=0;ct<4;ct++)
#pragma unroll
        for (int r=0;r<4;r++)
          Pw[(lq*4 + r)*APAD + ct*16 + l16] = f2bf(sc[ct][r]);
      asm volatile("s_waitcnt lgkmcnt(0)" ::: "memory");
#pragma unroll
      for (int ks=0;ks<2;ks++){
        short8 pf = *reinterpret_cast<const short8*>(Pw + l16*APAD + ks*32 + lq*8);
#pragma unroll
        for (int dt=0;dt<4;dt++){
          short8 vf = *reinterpret_cast<const short8*>(Vs + (dt*16 + l16)*APAD + ks*32 + lq*8);
          oacc[dt] = mfma16(pf, vf, oacc[dt]);
        }
      }
    }
#pragma unroll
    for (int dt=0;dt<4;dt++)
#pragma unroll
      for (int r=0;r<4;r++){
        const int qg = q0 + wid*16 + lq*4 + r;
        O[(size_t)(b*S_ + qg)*D_ + h*64 + dt*16 + l16] = f2bf(oacc[dt][r] / l_run[r]);
      }
  }
}

extern "C" void kernel_launch(void* const* d_in, const int* in_sizes, int n_in,
                              void* d_out, int out_size, void* d_ws, size_t ws_size,
                              hipStream_t stream){
  const float* x  = (const float*)d_in[0];
  const float* Wq = (const float*)d_in[1];
  const float* Wk = (const float*)d_in[2];
  const float* Wv = (const float*)d_in[3];
  const float* Wo = (const float*)d_in[4];
  char* ws = (char*)d_ws;
  u16* xb  = (u16*)(ws);                               // 16 MiB  x bf16
  u16* Wqb = (u16*)(ws + (16u<<20));                   // 2 MiB
  u16* Wkb = (u16*)(ws + (16u<<20) + (2u<<20));
  u16* Wvb = (u16*)(ws + (16u<<20) + (4u<<20));
  u16* Wob = (u16*)(ws + (16u<<20) + (6u<<20));
  u16* Qh  = (u16*)(ws + (24u<<20));                   // 16 MiB [BH][S][64]
  u16* Kh  = (u16*)(ws + (40u<<20));                   // 16 MiB
  u16* Vb  = (u16*)(ws + (56u<<20));                   // 16 MiB [B,S,D]
  u16* Vt  = (u16*)(ws + (72u<<20));                   // 16 MiB [BH][64][S]
  u16* Ob  = Vb;                                       // alias: V dead after vt_kernel

  cvt_kernel<<<8192, 256, 0, stream>>>(x,  xb,  2097152);
  cvt_kernel<<<1024, 256, 0, stream>>>(Wq, Wqb, 262144);
  cvt_kernel<<<1024, 256, 0, stream>>>(Wk, Wkb, 262144);
  cvt_kernel<<<1024, 256, 0, stream>>>(Wv, Wvb, 262144);
  cvt_kernel<<<1024, 256, 0, stream>>>(Wo, Wob, 262144);

  dim3 gg(8, 64);
  gemm_bt<1><<<gg, 256, 0, stream>>>(xb, Wqb, Qh, 8192, 1024, 1024);
  gemm_bt<1><<<gg, 256, 0, stream>>>(xb, Wkb, Kh, 8192, 1024, 1024);
  gemm_bt<0><<<gg, 256, 0, stream>>>(xb, Wvb, Vb, 8192, 1024, 1024);

  rope_kernel<<<16384, 256, 0, stream>>>(Qh, Kh);
  vt_kernel<<<dim3(32,64), 256, 0, stream>>>(Vb, Vt);
  attn_kernel<<<dim3(16,64), 256, 0, stream>>>(Qh, Kh, Vt, Ob);

  gemm_bt<2><<<gg, 256, 0, stream>>>(Ob, Wob, d_out, 8192, 1024, 1024);
}

// Round 4
// 292.602 us; speedup vs baseline: 1.5789x; 1.0105x over previous
//
#include <hip/hip_runtime.h>
#include <hip/hip_bf16.h>
#include <stdint.h>

#define B_ 4
#define S_ 2048
#define D_ 1024
#define H_ 16

typedef __attribute__((ext_vector_type(4))) float f32x4;
typedef __attribute__((ext_vector_type(8))) short short8;
typedef __attribute__((ext_vector_type(8))) unsigned short ushort8;
typedef unsigned short u16;
typedef unsigned int u32;

__device__ __forceinline__ u16 f2bf(float f){
  return __builtin_bit_cast(u16, __hip_bfloat16(f));
}
__device__ __forceinline__ float bf2f(u16 h){
  return __builtin_bit_cast(float, ((u32)h) << 16);
}
__device__ __forceinline__ f32x4 mfma16(short8 a, short8 b, f32x4 c){
  return __builtin_amdgcn_mfma_f32_16x16x32_bf16(a, b, c, 0, 0, 0);
}
__device__ __forceinline__ void gload16(const u16* g, u16* l){
  __builtin_amdgcn_global_load_lds((const __attribute__((address_space(1))) u32*)g,
                                   (__attribute__((address_space(3))) u32*)l, 16, 0, 0);
}

// ---------------- fp32 -> bf16 convert (4 elem / thread) ----------------
__global__ __launch_bounds__(256) void cvt_kernel(const float* __restrict__ in,
                                                  u16* __restrict__ out, int n4){
  int i = blockIdx.x * 256 + threadIdx.x;
  if (i >= n4) return;
  float4 v = reinterpret_cast<const float4*>(in)[i];
  uint2 o;
  o.x = (u32)f2bf(v.x) | ((u32)f2bf(v.y) << 16);
  o.y = (u32)f2bf(v.z) | ((u32)f2bf(v.w) << 16);
  reinterpret_cast<uint2*>(out)[i] = o;
}

// merged 4-weight convert: 1024 blocks per weight
__global__ __launch_bounds__(256) void cvtw_kernel(const float* __restrict__ w0, const float* __restrict__ w1,
                                                   const float* __restrict__ w2, const float* __restrict__ w3,
                                                   u16* __restrict__ o0, u16* __restrict__ o1,
                                                   u16* __restrict__ o2, u16* __restrict__ o3){
  const int which = blockIdx.x >> 10;
  const float* in = (which==0) ? w0 : (which==1) ? w1 : (which==2) ? w2 : w3;
  u16* out = (which==0) ? o0 : (which==1) ? o1 : (which==2) ? o2 : o3;
  const int i = (blockIdx.x & 1023) * 256 + threadIdx.x;
  float4 v = reinterpret_cast<const float4*>(in)[i];
  uint2 o;
  o.x = (u32)f2bf(v.x) | ((u32)f2bf(v.y) << 16);
  o.y = (u32)f2bf(v.z) | ((u32)f2bf(v.w) << 16);
  reinterpret_cast<uint2*>(out)[i] = o;
}

// ---------------- GEMM: C[M,N] = A[M,K] * B[N,K]^T (bf16 in, MODE out) ----
// m97 structure: global_load_lds width=16 into LINEAR LDS (no pad).
// MODE 0: bf16 row-major [M][N]; MODE 1: bf16 [B,H,S,HD]; MODE 2: f32 [M][N]
template<int MODE>
__global__ __launch_bounds__(256) void gemm_bt(const u16* __restrict__ A,
                                               const u16* __restrict__ Bw,
                                               void* __restrict__ C,
                                               int M, int N, int K){
  __shared__ __align__(16) u16 As[128*32];
  __shared__ __align__(16) u16 Bs[128*32];
  const int tid = threadIdx.x;
  const int lane = tid & 63, wid = tid >> 6;
  const int l16 = lane & 15, lq = lane >> 4;
  const int m0 = blockIdx.y * 128, n0 = blockIdx.x * 128;
  const int wr = (wid >> 1) * 64, wc = (wid & 1) * 64;
  // staging: wave wid covers 32 rows (2 gload_lds of 16 rows each)
  const int srow = wid*32 + (lane >> 2);
  const int scol = (lane & 3) * 8;
  const u16* Ag = A  + (size_t)(m0 + srow) * K + scol;
  const u16* Bg = Bw + (size_t)(n0 + srow) * K + scol;
  u16* AsW = As + wid*32*32;
  u16* BsW = Bs + wid*32*32;
  f32x4 acc[4][4] = {};
  for (int k0 = 0; k0 < K; k0 += 32){
    __syncthreads();
    gload16(Ag + k0,            AsW);
    gload16(Ag + 16*(size_t)K + k0, AsW + 16*32);
    gload16(Bg + k0,            BsW);
    gload16(Bg + 16*(size_t)K + k0, BsW + 16*32);
    __syncthreads();
    short8 af[4], bfr[4];
#pragma unroll
    for (int i=0;i<4;i++) af[i]  = *reinterpret_cast<const short8*>(As + (wr + i*16 + l16)*32 + lq*8);
#pragma unroll
    for (int i=0;i<4;i++) bfr[i] = *reinterpret_cast<const short8*>(Bs + (wc + i*16 + l16)*32 + lq*8);
#pragma unroll
    for (int i=0;i<4;i++)
#pragma unroll
      for (int j=0;j<4;j++) acc[i][j] = mfma16(af[i], bfr[j], acc[i][j]);
  }
#pragma unroll
  for (int i=0;i<4;i++){
#pragma unroll
    for (int j=0;j<4;j++){
#pragma unroll
      for (int r=0;r<4;r++){
        const int m = m0 + wr + i*16 + lq*4 + r;
        const int n = n0 + wc + j*16 + l16;
        const float v = acc[i][j][r];
        if (MODE == 2){
          reinterpret_cast<float*>(C)[(size_t)m * N + n] = v;
        } else if (MODE == 0){
          reinterpret_cast<u16*>(C)[(size_t)m * N + n] = f2bf(v);
        } else {
          const int b = m >> 11, s = m & 2047;    // S_=2048
          const int h = n >> 6,  hd = n & 63;     // HD=64
          reinterpret_cast<u16*>(C)[(((size_t)(b*H_ + h) * S_ + s) << 6) + hd] = f2bf(v);
        }
      }
    }
  }
}

// ---------------- RoPE in place on Q,K stored [B*H][S][64] ----------------
// Q additionally scaled by 0.125*log2(e) (folded softmax scale, exp2 domain).
__global__ __launch_bounds__(256) void rope_kernel(u16* __restrict__ Q, u16* __restrict__ Kk){
  const int idx = blockIdx.x * 256 + threadIdx.x;   // (bh:6)(s:11)(i:5)
  const int i  = idx & 31;
  const int s  = (idx >> 5) & 2047;
  const int bh = idx >> 16;
  const float ang = (float)s * __builtin_exp2f((float)i * -0.41524101186092032f); // theta^(-i/32)
  float sn, cs;
  __sincosf(ang, &sn, &cs);
  const float QS = 0.18033688011112043f;  // 0.125 * log2(e)
  const size_t base = ((size_t)bh * S_ + s) * 64 + 2*i;
  {
    unsigned q = *reinterpret_cast<unsigned*>(Q + base);
    float x1 = bf2f((u16)q), x2 = bf2f((u16)(q >> 16));
    *reinterpret_cast<unsigned*>(Q + base) =
      (u32)f2bf((x1*cs - x2*sn)*QS) | ((u32)f2bf((x1*sn + x2*cs)*QS) << 16);
  }
  {
    unsigned k = *reinterpret_cast<unsigned*>(Kk + base);
    float x1 = bf2f((u16)k), x2 = bf2f((u16)(k >> 16));
    *reinterpret_cast<unsigned*>(Kk + base) =
      (u32)f2bf(x1*cs - x2*sn) | ((u32)f2bf(x1*sn + x2*cs) << 16);
  }
}

// ---------------- V [B,S,D] -> V^T [B*H][HD=64][S] ----------------
__global__ __launch_bounds__(256) void vt_kernel(const u16* __restrict__ V, u16* __restrict__ Vt){
  __shared__ __align__(16) u16 t[64*80];
  const int bh = blockIdx.y, b = bh >> 4, h = bh & 15;
  const int s0 = blockIdx.x * 64;
  const int tid = threadIdx.x;
  const int r = tid >> 3, seg = tid & 7;
#pragma unroll
  for (int p=0;p<2;p++){
    const int row = r + p*32;   // s offset
    ushort8 v = *reinterpret_cast<const ushort8*>(V + (size_t)(b*S_ + s0 + row)*D_ + h*64 + seg*8);
    *reinterpret_cast<ushort8*>(t + row*80 + seg*8) = v;
  }
  __syncthreads();
#pragma unroll
  for (int p=0;p<2;p++){
    const int hd = r + p*32;
    ushort8 o;
#pragma unroll
    for (int j=0;j<8;j++) o[j] = t[(seg*8+j)*80 + hd];
    *reinterpret_cast<ushort8*>(Vt + ((size_t)bh*64 + hd)*S_ + s0 + seg*8) = o;
  }
}

// ---------------- causal flash attention ----------------
// Q,K: [BH][S][64] (Q pre-scaled into exp2 domain), Vt: [BH][64][S], O: [B,S,D] bf16
// APAD 68: bank stride 34 == +2 mod 32 -> frag reads hit 16 distinct banks.
// Work balance: block (bx,bh) processes q-tiles {31-bx, bx}: 33 KV-tiles each.
// Softmax: exp2 domain, defer-max (thr=8), lazy l-reduction (epilogue only).
#define APAD 68
__global__ __launch_bounds__(256) void attn_kernel(const u16* __restrict__ Q,
                                                   const u16* __restrict__ Kg,
                                                   const u16* __restrict__ Vt,
                                                   u16* __restrict__ O){
  __shared__ __align__(16) u16 Ks[64*APAD];
  __shared__ __align__(16) u16 Vs[64*APAD];
  __shared__ __align__(16) u16 Ps[4][16*APAD];
  const int bh = blockIdx.y;
  const int tid = threadIdx.x, wid = tid >> 6, lane = tid & 63;
  const int l16 = lane & 15, lq = lane >> 4;
  const u16* Qb = Q  + (size_t)bh * S_ * 64;
  const u16* Kb = Kg + (size_t)bh * S_ * 64;
  const u16* Vb = Vt + (size_t)bh * 64 * S_;
  const int b = bh >> 4, h = bh & 15;
  const int sr2 = tid >> 3, sc2 = (tid & 7) * 8;
  u16* Pw = &Ps[wid][0];

#pragma unroll 1
  for (int half = 0; half < 2; ++half){
    const int qt = half ? blockIdx.x : (31 - blockIdx.x);
    const int q0 = qt * 64;
    short8 qf[2];
#pragma unroll
    for (int ks=0;ks<2;ks++)
      qf[ks] = *reinterpret_cast<const short8*>(Qb + (size_t)(q0 + wid*16 + l16)*64 + ks*32 + lq*8);
    float m_run[4], l_run[4];
    f32x4 oacc[4];
#pragma unroll
    for (int j=0;j<4;j++){ m_run[j] = -1e30f; l_run[j] = 0.f; oacc[j] = (f32x4){0.f,0.f,0.f,0.f}; }

#pragma unroll 1
    for (int kt = 0; kt <= qt; ++kt){
      const int k0 = kt * 64;
      __syncthreads();
#pragma unroll
      for (int p=0;p<2;p++){
        const int row = sr2 + p*32;
        *reinterpret_cast<ushort8*>(Ks + row*APAD + sc2) =
          *reinterpret_cast<const ushort8*>(Kb + (size_t)(k0 + row)*64 + sc2);
        *reinterpret_cast<ushort8*>(Vs + row*APAD + sc2) =
          *reinterpret_cast<const ushort8*>(Vb + (size_t)row*S_ + k0 + sc2);
      }
      __syncthreads();
      f32x4 sc[4];
#pragma unroll
      for (int ct=0;ct<4;ct++){
        f32x4 a = (f32x4){0.f,0.f,0.f,0.f};
#pragma unroll
        for (int ks=0;ks<2;ks++){
          short8 kf = *reinterpret_cast<const short8*>(Ks + (ct*16 + l16)*APAD + ks*32 + lq*8);
          a = mfma16(qf[ks], kf, a);
        }
        sc[ct] = a;
      }
      if (kt == qt){   // mask only the diagonal tile
#pragma unroll
        for (int ct=0;ct<4;ct++){
          const int kg = ct*16 + l16;
#pragma unroll
          for (int r=0;r<4;r++){
            const int qg = wid*16 + lq*4 + r;
            if (kg > qg) sc[ct][r] = -1e30f;
          }
        }
      }
      // defer-max: cheap per-lane lower-bound check
      float lmx[4];
      bool grow = false;
#pragma unroll
      for (int r=0;r<4;r++){
        lmx[r] = fmaxf(fmaxf(sc[0][r], sc[1][r]), fmaxf(sc[2][r], sc[3][r]));
        grow = grow || (lmx[r] > m_run[r] + 8.f);
      }
      if (__any(grow)){
#pragma unroll
        for (int r=0;r<4;r++){
          float mx = lmx[r];
#pragma unroll
          for (int msk=1; msk<16; msk<<=1) mx = fmaxf(mx, __shfl_xor(mx, msk, 64));
          mx = fmaxf(mx, m_run[r]);
          const float alpha = __builtin_exp2f(m_run[r] - mx);
          m_run[r] = mx;
          l_run[r] *= alpha;
#pragma unroll
          for (int dt=0;dt<4;dt++) oacc[dt][r] *= alpha;
        }
      }
#pragma unroll
      for (int r=0;r<4;r++){
        float s0e = __builtin_exp2f(sc[0][r] - m_run[r]);
        float s1e = __builtin_exp2f(sc[1][r] - m_run[r]);
        float s2e = __builtin_exp2f(sc[2][r] - m_run[r]);
        float s3e = __builtin_exp2f(sc[3][r] - m_run[r]);
        sc[0][r]=s0e; sc[1][r]=s1e; sc[2][r]=s2e; sc[3][r]=s3e;
        l_run[r] += (s0e + s1e) + (s2e + s3e);   // per-lane partial; reduced in epilogue
      }
#pragma unroll
      for (int ct=0;ct<4;ct++)
#pragma unroll
        for (int r=0;r<4;r++)
          Pw[(lq*4 + r)*APAD + ct*16 + l16] = f2bf(sc[ct][r]);
      asm volatile("s_waitcnt lgkmcnt(0)" ::: "memory");
#pragma unroll
      for (int ks=0;ks<2;ks++){
        short8 pf = *reinterpret_cast<const short8*>(Pw + l16*APAD + ks*32 + lq*8);
#pragma unroll
        for (int dt=0;dt<4;dt++){
          short8 vf = *reinterpret_cast<const short8*>(Vs + (dt*16 + l16)*APAD + ks*32 + lq*8);
          oacc[dt] = mfma16(pf, vf, oacc[dt]);
        }
      }
    }
    float linv[4];
#pragma unroll
    for (int r=0;r<4;r++){
      float lt = l_run[r];
#pragma unroll
      for (int msk=1; msk<16; msk<<=1) lt += __shfl_xor(lt, msk, 64);
      linv[r] = __builtin_amdgcn_rcpf(lt);
    }
#pragma unroll
    for (int dt=0;dt<4;dt++)
#pragma unroll
      for (int r=0;r<4;r++){
        const int qg = q0 + wid*16 + lq*4 + r;
        O[(size_t)(b*S_ + qg)*D_ + h*64 + dt*16 + l16] = f2bf(oacc[dt][r] * linv[r]);
      }
  }
}

extern "C" void kernel_launch(void* const* d_in, const int* in_sizes, int n_in,
                              void* d_out, int out_size, void* d_ws, size_t ws_size,
                              hipStream_t stream){
  const float* x  = (const float*)d_in[0];
  const float* Wq = (const float*)d_in[1];
  const float* Wk = (const float*)d_in[2];
  const float* Wv = (const float*)d_in[3];
  const float* Wo = (const float*)d_in[4];
  char* ws = (char*)d_ws;
  u16* xb  = (u16*)(ws);                               // 16 MiB  x bf16
  u16* Wqb = (u16*)(ws + (16u<<20));                   // 2 MiB
  u16* Wkb = (u16*)(ws + (16u<<20) + (2u<<20));
  u16* Wvb = (u16*)(ws + (16u<<20) + (4u<<20));
  u16* Wob = (u16*)(ws + (16u<<20) + (6u<<20));
  u16* Qh  = (u16*)(ws + (24u<<20));                   // 16 MiB [BH][S][64]
  u16* Kh  = (u16*)(ws + (40u<<20));                   // 16 MiB
  u16* Vb  = (u16*)(ws + (56u<<20));                   // 16 MiB [B,S,D]
  u16* Vt  = (u16*)(ws + (72u<<20));                   // 16 MiB [BH][64][S]
  u16* Ob  = Vb;                                       // alias: V dead after vt_kernel

  cvt_kernel<<<8192, 256, 0, stream>>>(x, xb, 2097152);
  cvtw_kernel<<<4096, 256, 0, stream>>>(Wq, Wk, Wv, Wo, Wqb, Wkb, Wvb, Wob);

  dim3 gg(8, 64);
  gemm_bt<1><<<gg, 256, 0, stream>>>(xb, Wqb, Qh, 8192, 1024, 1024);
  gemm_bt<1><<<gg, 256, 0, stream>>>(xb, Wkb, Kh, 8192, 1024, 1024);
  gemm_bt<0><<<gg, 256, 0, stream>>>(xb, Wvb, Vb, 8192, 1024, 1024);

  rope_kernel<<<16384, 256, 0, stream>>>(Qh, Kh);
  vt_kernel<<<dim3(32,64), 256, 0, stream>>>(Vb, Vt);
  attn_kernel<<<dim3(16,64), 256, 0, stream>>>(Qh, Kh, Vt, Ob);

  gemm_bt<2><<<gg, 256, 0, stream>>>(Ob, Wob, d_out, 8192, 1024, 1024);
}